// Round 2
// baseline (470.501 us; speedup 1.0000x reference)
//
#include <hip/hip_runtime.h>
#include <hip/hip_fp16.h>

typedef __attribute__((ext_vector_type(8))) _Float16 half8;
typedef __attribute__((ext_vector_type(4))) float float4v;

#define LDP 40  // padded LDS row stride in f16 (80B -> bank-conflict ~2-way, free)

// ---------------- degree / CSR build ----------------

__global__ __launch_bounds__(256) void k_deg(const int* __restrict__ dst, int* __restrict__ deg, int E) {
    int e = blockIdx.x * 256 + threadIdx.x;
    if (e < E) atomicAdd(&deg[dst[e]], 1);
}

__global__ __launch_bounds__(256) void k_dinv(const int* __restrict__ deg, float* __restrict__ dinv, int N) {
    int i = blockIdx.x * 256 + threadIdx.x;
    if (i < N) dinv[i] = rsqrtf((float)(deg[i] + 1));  // +1 = self-loop
}

// single-block exclusive scan of deg -> rowptr (N ~ 50000)
__global__ __launch_bounds__(256) void k_scan(const int* __restrict__ deg, int* __restrict__ rowptr, int N) {
    __shared__ int sums[256];
    int t = threadIdx.x;
    int CH = (N + 255) / 256;
    int base = t * CH;
    int s = 0;
    for (int i = 0; i < CH; i++) {
        int idx = base + i;
        if (idx < N) s += deg[idx];
    }
    sums[t] = s;
    __syncthreads();
    if (t == 0) {
        int run = 0;
        for (int i = 0; i < 256; i++) { int v = sums[i]; sums[i] = run; run += v; }
    }
    __syncthreads();
    int run = sums[t];
    for (int i = 0; i < CH; i++) {
        int idx = base + i;
        if (idx < N) { rowptr[idx] = run; run += deg[idx]; }
    }
    if (t == 255) rowptr[N] = run;
}

__global__ __launch_bounds__(256) void k_fill(const int* __restrict__ src, const int* __restrict__ dst,
                                              const int* __restrict__ rowptr, int* __restrict__ rowcnt,
                                              int* __restrict__ csr, int E) {
    int e = blockIdx.x * 256 + threadIdx.x;
    if (e < E) {
        int d = dst[e];
        int pos = rowptr[d] + atomicAdd(&rowcnt[d], 1);
        csr[pos] = src[e];
    }
}

// ---------------- weight prep: transpose + f16 convert ----------------
// Wt1[j][k] = W1[k][j]; Wct[j][k] = (j<128 ? Wmu[k][j] : Wls[k][j-128])
__global__ __launch_bounds__(256) void k_wt(const float* __restrict__ W1, const float* __restrict__ Wmu,
                                            const float* __restrict__ Wls, _Float16* __restrict__ Wt1,
                                            _Float16* __restrict__ Wct) {
    int b = blockIdx.x;
    int t = threadIdx.x;  // k index
    if (b < 256) {
        Wt1[b * 256 + t] = (_Float16)W1[t * 256 + b];
    } else {
        int j = b - 256;
        float v = (j < 128) ? Wmu[t * 128 + j] : Wls[t * 128 + (j - 128)];
        Wct[j * 256 + t] = (_Float16)v;
    }
}

// ---------------- GEMM: [M x 256] @ [256 x 256] via mfma_f32_16x16x32_f16 ----------------
// AF32: A operand is f32 (converted during staging); else f16.
// OUTF32: write f32 to d_out split mu/ls with bias; else write f16 (no bias).
template <int AF32, int OUTF32>
__global__ __launch_bounds__(256) void gemm_k(const void* __restrict__ Aptr, const _Float16* __restrict__ Bt,
                                              const float* __restrict__ bmu, const float* __restrict__ bls,
                                              void* __restrict__ outp, int M, size_t split) {
    __shared__ _Float16 As[128 * LDP];
    __shared__ _Float16 Bs[128 * LDP];
    const int t = threadIdx.x;
    const int lane = t & 63;
    const int wid = t >> 6;
    const int bm = blockIdx.x * 128;
    const int bn = blockIdx.y * 128;
    const int wm = (wid & 1) * 64;
    const int wn = (wid >> 1) * 64;

    float4v acc[4][4];
#pragma unroll
    for (int i = 0; i < 4; i++)
#pragma unroll
        for (int j = 0; j < 4; j++) acc[i][j] = (float4v){0.f, 0.f, 0.f, 0.f};

    for (int kt = 0; kt < 256; kt += 32) {
        // ---- stage A tile: 128 rows x 32 k ----
        if (AF32) {
            const float* A = (const float*)Aptr;
            int row = t >> 1;
            int ko = (t & 1) * 16;
            int gr = bm + row; if (gr >= M) gr = M - 1;
            const float4v* p = (const float4v*)(A + (size_t)gr * 256 + kt + ko);
            float4v v0 = p[0], v1 = p[1], v2 = p[2], v3 = p[3];
            half8 h0, h1;
            h0[0] = (_Float16)v0[0]; h0[1] = (_Float16)v0[1]; h0[2] = (_Float16)v0[2]; h0[3] = (_Float16)v0[3];
            h0[4] = (_Float16)v1[0]; h0[5] = (_Float16)v1[1]; h0[6] = (_Float16)v1[2]; h0[7] = (_Float16)v1[3];
            h1[0] = (_Float16)v2[0]; h1[1] = (_Float16)v2[1]; h1[2] = (_Float16)v2[2]; h1[3] = (_Float16)v2[3];
            h1[4] = (_Float16)v3[0]; h1[5] = (_Float16)v3[1]; h1[6] = (_Float16)v3[2]; h1[7] = (_Float16)v3[3];
            *(half8*)&As[row * LDP + ko] = h0;
            *(half8*)&As[row * LDP + ko + 8] = h1;
        } else {
            const _Float16* A = (const _Float16*)Aptr;
#pragma unroll
            for (int m = 0; m < 2; m++) {
                int c = t + m * 256;
                int row = c >> 2, ks = (c & 3) * 8;
                int gr = bm + row; if (gr >= M) gr = M - 1;
                half8 v = *(const half8*)(A + (size_t)gr * 256 + kt + ks);
                *(half8*)&As[row * LDP + ks] = v;
            }
        }
        // ---- stage B tile (Bt is [256 cols][256 k], row-major) ----
#pragma unroll
        for (int m = 0; m < 2; m++) {
            int c = t + m * 256;
            int row = c >> 2, ks = (c & 3) * 8;
            half8 v = *(const half8*)(Bt + (size_t)(bn + row) * 256 + kt + ks);
            *(half8*)&Bs[row * LDP + ks] = v;
        }
        __syncthreads();

        const int kg = (lane >> 4) * 8;
        const int fr = lane & 15;
        half8 af[4], bf[4];
#pragma unroll
        for (int f = 0; f < 4; f++) af[f] = *(const half8*)&As[(wm + f * 16 + fr) * LDP + kg];
#pragma unroll
        for (int f = 0; f < 4; f++) bf[f] = *(const half8*)&Bs[(wn + f * 16 + fr) * LDP + kg];
#pragma unroll
        for (int i = 0; i < 4; i++)
#pragma unroll
            for (int j = 0; j < 4; j++)
                acc[i][j] = __builtin_amdgcn_mfma_f32_16x16x32_f16(af[i], bf[j], acc[i][j], 0, 0, 0);
        __syncthreads();
    }

    // ---- epilogue: D mapping col=lane&15, row=(lane>>4)*4+reg ----
    const int fc = lane & 15;
    const int rq = (lane >> 4) * 4;
    if (OUTF32) {
        float* out = (float*)outp;
#pragma unroll
        for (int i = 0; i < 4; i++) {
#pragma unroll
            for (int j = 0; j < 4; j++) {
                int col = bn + wn + j * 16 + fc;
                float bias = (col < 128) ? bmu[col] : bls[col - 128];
#pragma unroll
                for (int r = 0; r < 4; r++) {
                    int row = bm + wm + i * 16 + rq + r;
                    if (row < M) {
                        size_t o = (col < 128) ? ((size_t)row * 128 + col)
                                               : (split + (size_t)row * 128 + (col - 128));
                        out[o] = acc[i][j][r] + bias;
                    }
                }
            }
        }
    } else {
        _Float16* out = (_Float16*)outp;
#pragma unroll
        for (int i = 0; i < 4; i++) {
#pragma unroll
            for (int j = 0; j < 4; j++) {
                int col = bn + wn + j * 16 + fc;
#pragma unroll
                for (int r = 0; r < 4; r++) {
                    int row = bm + wm + i * 16 + rq + r;
                    if (row < M) out[(size_t)row * 256 + col] = (_Float16)acc[i][j][r];
                }
            }
        }
    }
}

// ---------------- aggregation: out[n] = sum_{e: dst=n} in[src_e]*dinv[s]*dinv[n] + in[n]*dinv[n]^2 ----------------
// 32 lanes per node, 8 f16 features per lane. Optional bias + relu, f16 output.
__global__ __launch_bounds__(256) void k_agg(const _Float16* __restrict__ in, _Float16* __restrict__ out,
                                             const float* __restrict__ dinv, const int* __restrict__ rowptr,
                                             const int* __restrict__ csr, const float* __restrict__ bias,
                                             int relu, int N) {
    int g = blockIdx.x * 8 + (threadIdx.x >> 5);
    int lane = threadIdx.x & 31;
    if (g >= N) return;
    float dd = dinv[g];
    int beg = rowptr[g], end = rowptr[g + 1];

    float acc[8];
    {
        half8 hv = *(const half8*)(in + (size_t)g * 256 + lane * 8);
        float ws = dd * dd;
#pragma unroll
        for (int j = 0; j < 8; j++) acc[j] = (float)hv[j] * ws;
    }
    for (int e = beg; e < end; ++e) {
        int s = csr[e];
        float w = dinv[s] * dd;
        half8 v = *(const half8*)(in + (size_t)s * 256 + lane * 8);
#pragma unroll
        for (int j = 0; j < 8; j++) acc[j] += (float)v[j] * w;
    }
    if (bias) {
#pragma unroll
        for (int j = 0; j < 8; j++) acc[j] += bias[lane * 8 + j];
    }
    if (relu) {
#pragma unroll
        for (int j = 0; j < 8; j++) acc[j] = fmaxf(acc[j], 0.f);
    }
    half8 o;
#pragma unroll
    for (int j = 0; j < 8; j++) o[j] = (_Float16)acc[j];
    *(half8*)(out + (size_t)g * 256 + lane * 8) = o;
}

// ---------------- launch ----------------

extern "C" void kernel_launch(void* const* d_in, const int* in_sizes, int n_in,
                              void* d_out, int out_size, void* d_ws, size_t ws_size,
                              hipStream_t stream) {
    const float* x   = (const float*)d_in[0];
    const int*   ei  = (const int*)d_in[1];
    const float* W1  = (const float*)d_in[2];
    const float* b1  = (const float*)d_in[3];
    const float* Wmu = (const float*)d_in[4];
    const float* bmu = (const float*)d_in[5];
    const float* Wls = (const float*)d_in[6];
    const float* bls = (const float*)d_in[7];
    const int N = in_sizes[0] / 256;
    const int E = in_sizes[1] / 2;
    const int* esrc = ei;
    const int* edst = ei + E;

    char* ws = (char*)d_ws;
    size_t off = 0;
    auto alloc = [&](size_t bytes) -> void* {
        void* p = ws + off;
        off += (bytes + 255) & ~(size_t)255;
        return p;
    };
    _Float16* h1  = (_Float16*)alloc((size_t)N * 256 * 2);  // layer1 pre-agg; reused as g (layer2 agg out)
    _Float16* hb  = (_Float16*)alloc((size_t)N * 256 * 2);  // h = relu(agg1 + b1)
    _Float16* Wt1 = (_Float16*)alloc(256 * 256 * 2);
    _Float16* Wct = (_Float16*)alloc(256 * 256 * 2);
    float* dinv   = (float*)alloc((size_t)N * 4);
    int* deg      = (int*)alloc((size_t)N * 4);
    int* rowptr   = (int*)alloc((size_t)(N + 1) * 4);
    int* rowcnt   = (int*)alloc((size_t)N * 4);
    int* csr      = (int*)alloc((size_t)E * 4);

    hipMemsetAsync(deg, 0, (size_t)N * 4, stream);
    hipMemsetAsync(rowcnt, 0, (size_t)N * 4, stream);

    k_deg<<<(E + 255) / 256, 256, 0, stream>>>(edst, deg, E);
    k_dinv<<<(N + 255) / 256, 256, 0, stream>>>(deg, dinv, N);
    k_scan<<<1, 256, 0, stream>>>(deg, rowptr, N);
    k_fill<<<(E + 255) / 256, 256, 0, stream>>>(esrc, edst, rowptr, rowcnt, csr, E);
    k_wt<<<512, 256, 0, stream>>>(W1, Wmu, Wls, Wt1, Wct);

    dim3 gg((N + 127) / 128, 2);
    gemm_k<1, 0><<<gg, 256, 0, stream>>>(x, Wt1, nullptr, nullptr, h1, N, 0);
    k_agg<<<(N + 7) / 8, 256, 0, stream>>>(h1, hb, dinv, rowptr, csr, b1, 1, N);
    k_agg<<<(N + 7) / 8, 256, 0, stream>>>(hb, h1, dinv, rowptr, csr, nullptr, 0, N);
    gemm_k<0, 1><<<gg, 256, 0, stream>>>(h1, Wct, bmu, bls, d_out, N, (size_t)N * 128);
}

// Round 3
// 373.011 us; speedup vs baseline: 1.2614x; 1.2614x over previous
//
#include <hip/hip_runtime.h>
#include <hip/hip_fp16.h>

typedef __attribute__((ext_vector_type(8))) _Float16 half8;
typedef __attribute__((ext_vector_type(4))) float float4v;

#define LDP 40  // padded LDS row stride in f16 (80B -> bank-conflict ~2-way, free)

// ---------------- degree / CSR build ----------------

__global__ __launch_bounds__(256) void k_deg(const int* __restrict__ dst, int* __restrict__ deg, int E) {
    int e = blockIdx.x * 256 + threadIdx.x;
    if (e < E) atomicAdd(&deg[dst[e]], 1);
}

// ---- parallel exclusive scan of deg -> rowptr (3 phases), dinv fused into phase 1 ----

__global__ __launch_bounds__(256) void k_scan1(const int* __restrict__ deg, int* __restrict__ rowptr,
                                               int* __restrict__ bsum, float* __restrict__ dinv, int N) {
    __shared__ int sm[256];
    const int t = threadIdx.x;
    const int i = blockIdx.x * 256 + t;
    int v = (i < N) ? deg[i] : 0;
    if (i < N) dinv[i] = rsqrtf((float)(v + 1));  // +1 = self-loop
    int x = v;
    sm[t] = x;
    __syncthreads();
#pragma unroll
    for (int off = 1; off < 256; off <<= 1) {
        int y = (t >= off) ? sm[t - off] : 0;
        __syncthreads();
        x += y;
        sm[t] = x;
        __syncthreads();
    }
    if (i < N) rowptr[i] = x - v;      // exclusive within block
    if (t == 255) bsum[blockIdx.x] = x; // block total
}

__global__ __launch_bounds__(256) void k_scan2(int* __restrict__ bsum, int* __restrict__ rowptr, int nb, int N) {
    __shared__ int sm[256];
    const int t = threadIdx.x;
    int v = (t < nb) ? bsum[t] : 0;
    int x = v;
    sm[t] = x;
    __syncthreads();
#pragma unroll
    for (int off = 1; off < 256; off <<= 1) {
        int y = (t >= off) ? sm[t - off] : 0;
        __syncthreads();
        x += y;
        sm[t] = x;
        __syncthreads();
    }
    if (t < nb) bsum[t] = x - v;  // exclusive block offsets
    if (t == 255) rowptr[N] = x;  // grand total = E
}

__global__ __launch_bounds__(256) void k_scan3(int* __restrict__ rowptr, const int* __restrict__ bsum, int N) {
    int i = blockIdx.x * 256 + threadIdx.x;
    if (i < N) rowptr[i] += bsum[blockIdx.x];
}

__global__ __launch_bounds__(256) void k_fill(const int* __restrict__ src, const int* __restrict__ dst,
                                              const int* __restrict__ rowptr, int* __restrict__ rowcnt,
                                              int* __restrict__ csr, int E) {
    int e = blockIdx.x * 256 + threadIdx.x;
    if (e < E) {
        int d = dst[e];
        int pos = rowptr[d] + atomicAdd(&rowcnt[d], 1);
        csr[pos] = src[e];
    }
}

// ---------------- weight prep: transpose + f16 convert ----------------
// Wt1[j][k] = W1[k][j]; Wct[j][k] = (j<128 ? Wmu[k][j] : Wls[k][j-128])
__global__ __launch_bounds__(256) void k_wt(const float* __restrict__ W1, const float* __restrict__ Wmu,
                                            const float* __restrict__ Wls, _Float16* __restrict__ Wt1,
                                            _Float16* __restrict__ Wct) {
    int b = blockIdx.x;
    int t = threadIdx.x;  // k index
    if (b < 256) {
        Wt1[b * 256 + t] = (_Float16)W1[t * 256 + b];
    } else {
        int j = b - 256;
        float v = (j < 128) ? Wmu[t * 128 + j] : Wls[t * 128 + (j - 128)];
        Wct[j * 256 + t] = (_Float16)v;
    }
}

// ---------------- GEMM: [M x 256] @ [256 x 256] via mfma_f32_16x16x32_f16 ----------------
// AF32: A operand is f32 (converted during staging); else f16.
// OUTF32: write f32 to d_out split mu/ls with bias; else write f16 (no bias).
template <int AF32, int OUTF32>
__global__ __launch_bounds__(256) void gemm_k(const void* __restrict__ Aptr, const _Float16* __restrict__ Bt,
                                              const float* __restrict__ bmu, const float* __restrict__ bls,
                                              void* __restrict__ outp, int M, size_t split) {
    __shared__ _Float16 As[128 * LDP];
    __shared__ _Float16 Bs[128 * LDP];
    const int t = threadIdx.x;
    const int lane = t & 63;
    const int wid = t >> 6;
    const int bm = blockIdx.x * 128;
    const int bn = blockIdx.y * 128;
    const int wm = (wid & 1) * 64;
    const int wn = (wid >> 1) * 64;

    float4v acc[4][4];
#pragma unroll
    for (int i = 0; i < 4; i++)
#pragma unroll
        for (int j = 0; j < 4; j++) acc[i][j] = (float4v){0.f, 0.f, 0.f, 0.f};

    for (int kt = 0; kt < 256; kt += 32) {
        // ---- stage A tile: 128 rows x 32 k ----
        if (AF32) {
            const float* A = (const float*)Aptr;
            int row = t >> 1;
            int ko = (t & 1) * 16;
            int gr = bm + row; if (gr >= M) gr = M - 1;
            const float4v* p = (const float4v*)(A + (size_t)gr * 256 + kt + ko);
            float4v v0 = p[0], v1 = p[1], v2 = p[2], v3 = p[3];
            half8 h0, h1;
            h0[0] = (_Float16)v0[0]; h0[1] = (_Float16)v0[1]; h0[2] = (_Float16)v0[2]; h0[3] = (_Float16)v0[3];
            h0[4] = (_Float16)v1[0]; h0[5] = (_Float16)v1[1]; h0[6] = (_Float16)v1[2]; h0[7] = (_Float16)v1[3];
            h1[0] = (_Float16)v2[0]; h1[1] = (_Float16)v2[1]; h1[2] = (_Float16)v2[2]; h1[3] = (_Float16)v2[3];
            h1[4] = (_Float16)v3[0]; h1[5] = (_Float16)v3[1]; h1[6] = (_Float16)v3[2]; h1[7] = (_Float16)v3[3];
            *(half8*)&As[row * LDP + ko] = h0;
            *(half8*)&As[row * LDP + ko + 8] = h1;
        } else {
            const _Float16* A = (const _Float16*)Aptr;
#pragma unroll
            for (int m = 0; m < 2; m++) {
                int c = t + m * 256;
                int row = c >> 2, ks = (c & 3) * 8;
                int gr = bm + row; if (gr >= M) gr = M - 1;
                half8 v = *(const half8*)(A + (size_t)gr * 256 + kt + ks);
                *(half8*)&As[row * LDP + ks] = v;
            }
        }
        // ---- stage B tile (Bt is [256 cols][256 k], row-major) ----
#pragma unroll
        for (int m = 0; m < 2; m++) {
            int c = t + m * 256;
            int row = c >> 2, ks = (c & 3) * 8;
            half8 v = *(const half8*)(Bt + (size_t)(bn + row) * 256 + kt + ks);
            *(half8*)&Bs[row * LDP + ks] = v;
        }
        __syncthreads();

        const int kg = (lane >> 4) * 8;
        const int fr = lane & 15;
        half8 af[4], bf[4];
#pragma unroll
        for (int f = 0; f < 4; f++) af[f] = *(const half8*)&As[(wm + f * 16 + fr) * LDP + kg];
#pragma unroll
        for (int f = 0; f < 4; f++) bf[f] = *(const half8*)&Bs[(wn + f * 16 + fr) * LDP + kg];
#pragma unroll
        for (int i = 0; i < 4; i++)
#pragma unroll
            for (int j = 0; j < 4; j++)
                acc[i][j] = __builtin_amdgcn_mfma_f32_16x16x32_f16(af[i], bf[j], acc[i][j], 0, 0, 0);
        __syncthreads();
    }

    // ---- epilogue: D mapping col=lane&15, row=(lane>>4)*4+reg ----
    const int fc = lane & 15;
    const int rq = (lane >> 4) * 4;
    if (OUTF32) {
        float* out = (float*)outp;
#pragma unroll
        for (int i = 0; i < 4; i++) {
#pragma unroll
            for (int j = 0; j < 4; j++) {
                int col = bn + wn + j * 16 + fc;
                float bias = (col < 128) ? bmu[col] : bls[col - 128];
#pragma unroll
                for (int r = 0; r < 4; r++) {
                    int row = bm + wm + i * 16 + rq + r;
                    if (row < M) {
                        size_t o = (col < 128) ? ((size_t)row * 128 + col)
                                               : (split + (size_t)row * 128 + (col - 128));
                        out[o] = acc[i][j][r] + bias;
                    }
                }
            }
        }
    } else {
        _Float16* out = (_Float16*)outp;
#pragma unroll
        for (int i = 0; i < 4; i++) {
#pragma unroll
            for (int j = 0; j < 4; j++) {
                int col = bn + wn + j * 16 + fc;
#pragma unroll
                for (int r = 0; r < 4; r++) {
                    int row = bm + wm + i * 16 + rq + r;
                    if (row < M) out[(size_t)row * 256 + col] = (_Float16)acc[i][j][r];
                }
            }
        }
    }
}

// ---------------- aggregation: out[n] = sum_{e: dst=n} in[src_e]*dinv[s]*dinv[n] + in[n]*dinv[n]^2 ----------------
// 32 lanes per node, 8 f16 features per lane. Optional bias + relu, f16 output.
__global__ __launch_bounds__(256) void k_agg(const _Float16* __restrict__ in, _Float16* __restrict__ out,
                                             const float* __restrict__ dinv, const int* __restrict__ rowptr,
                                             const int* __restrict__ csr, const float* __restrict__ bias,
                                             int relu, int N) {
    int g = blockIdx.x * 8 + (threadIdx.x >> 5);
    int lane = threadIdx.x & 31;
    if (g >= N) return;
    float dd = dinv[g];
    int beg = rowptr[g], end = rowptr[g + 1];

    float acc[8];
    {
        half8 hv = *(const half8*)(in + (size_t)g * 256 + lane * 8);
        float ws = dd * dd;
#pragma unroll
        for (int j = 0; j < 8; j++) acc[j] = (float)hv[j] * ws;
    }
    for (int e = beg; e < end; ++e) {
        int s = csr[e];
        float w = dinv[s] * dd;
        half8 v = *(const half8*)(in + (size_t)s * 256 + lane * 8);
#pragma unroll
        for (int j = 0; j < 8; j++) acc[j] += (float)v[j] * w;
    }
    if (bias) {
#pragma unroll
        for (int j = 0; j < 8; j++) acc[j] += bias[lane * 8 + j];
    }
    if (relu) {
#pragma unroll
        for (int j = 0; j < 8; j++) acc[j] = fmaxf(acc[j], 0.f);
    }
    half8 o;
#pragma unroll
    for (int j = 0; j < 8; j++) o[j] = (_Float16)acc[j];
    *(half8*)(out + (size_t)g * 256 + lane * 8) = o;
}

// ---------------- launch ----------------

extern "C" void kernel_launch(void* const* d_in, const int* in_sizes, int n_in,
                              void* d_out, int out_size, void* d_ws, size_t ws_size,
                              hipStream_t stream) {
    const float* x   = (const float*)d_in[0];
    const int*   ei  = (const int*)d_in[1];
    const float* W1  = (const float*)d_in[2];
    const float* b1  = (const float*)d_in[3];
    const float* Wmu = (const float*)d_in[4];
    const float* bmu = (const float*)d_in[5];
    const float* Wls = (const float*)d_in[6];
    const float* bls = (const float*)d_in[7];
    const int N = in_sizes[0] / 256;
    const int E = in_sizes[1] / 2;
    const int* esrc = ei;
    const int* edst = ei + E;

    char* ws = (char*)d_ws;
    size_t off = 0;
    auto alloc = [&](size_t bytes) -> void* {
        void* p = ws + off;
        off += (bytes + 255) & ~(size_t)255;
        return p;
    };
    _Float16* h1  = (_Float16*)alloc((size_t)N * 256 * 2);  // layer1 pre-agg; reused as g (layer2 agg out)
    _Float16* hb  = (_Float16*)alloc((size_t)N * 256 * 2);  // h = relu(agg1 + b1)
    _Float16* Wt1 = (_Float16*)alloc(256 * 256 * 2);
    _Float16* Wct = (_Float16*)alloc(256 * 256 * 2);
    float* dinv   = (float*)alloc((size_t)N * 4);
    int* degcnt   = (int*)alloc((size_t)N * 2 * 4);  // [deg | rowcnt] contiguous -> one memset
    int* deg      = degcnt;
    int* rowcnt   = degcnt + N;
    int* rowptr   = (int*)alloc((size_t)(N + 1) * 4);
    int* bsum     = (int*)alloc(256 * 4);
    int* csr      = (int*)alloc((size_t)E * 4);

    const int nb = (N + 255) / 256;  // scan blocks (196 for N=50000; must be <= 256)

    hipMemsetAsync(degcnt, 0, (size_t)N * 2 * 4, stream);

    k_deg<<<(E + 255) / 256, 256, 0, stream>>>(edst, deg, E);
    k_scan1<<<nb, 256, 0, stream>>>(deg, rowptr, bsum, dinv, N);
    k_scan2<<<1, 256, 0, stream>>>(bsum, rowptr, nb, N);
    k_scan3<<<nb, 256, 0, stream>>>(rowptr, bsum, N);
    k_fill<<<(E + 255) / 256, 256, 0, stream>>>(esrc, edst, rowptr, rowcnt, csr, E);
    k_wt<<<512, 256, 0, stream>>>(W1, Wmu, Wls, Wt1, Wct);

    dim3 gg((N + 127) / 128, 2);
    gemm_k<1, 0><<<gg, 256, 0, stream>>>(x, Wt1, nullptr, nullptr, h1, N, 0);
    k_agg<<<(N + 7) / 8, 256, 0, stream>>>(h1, hb, dinv, rowptr, csr, b1, 1, N);
    k_agg<<<(N + 7) / 8, 256, 0, stream>>>(hb, h1, dinv, rowptr, csr, nullptr, 0, N);
    gemm_k<0, 1><<<gg, 256, 0, stream>>>(h1, Wct, bmu, bls, d_out, N, (size_t)N * 128);
}

// Round 4
// 360.722 us; speedup vs baseline: 1.3043x; 1.0341x over previous
//
#include <hip/hip_runtime.h>
#include <hip/hip_fp16.h>

typedef __attribute__((ext_vector_type(8))) _Float16 half8;
typedef __attribute__((ext_vector_type(4))) _Float16 half4;
typedef __attribute__((ext_vector_type(4))) float float4v;

#define LDP2 72  // padded LDS row stride in f16 for BK=64 (144B -> stride 36 banks -> 2-way, free)

// ---------------- degree / CSR build ----------------

__global__ __launch_bounds__(256) void k_deg(const int* __restrict__ dst, int* __restrict__ deg, int E) {
    int e = blockIdx.x * 256 + threadIdx.x;
    if (e < E) atomicAdd(&deg[dst[e]], 1);
}

// ---- parallel exclusive scan of deg -> rowptr (3 phases), dinv fused into phase 1 ----

__global__ __launch_bounds__(256) void k_scan1(const int* __restrict__ deg, int* __restrict__ rowptr,
                                               int* __restrict__ bsum, float* __restrict__ dinv, int N) {
    __shared__ int sm[256];
    const int t = threadIdx.x;
    const int i = blockIdx.x * 256 + t;
    int v = (i < N) ? deg[i] : 0;
    if (i < N) dinv[i] = rsqrtf((float)(v + 1));  // +1 = self-loop
    int x = v;
    sm[t] = x;
    __syncthreads();
#pragma unroll
    for (int off = 1; off < 256; off <<= 1) {
        int y = (t >= off) ? sm[t - off] : 0;
        __syncthreads();
        x += y;
        sm[t] = x;
        __syncthreads();
    }
    if (i < N) rowptr[i] = x - v;      // exclusive within block
    if (t == 255) bsum[blockIdx.x] = x; // block total
}

__global__ __launch_bounds__(256) void k_scan2(int* __restrict__ bsum, int* __restrict__ rowptr, int nb, int N) {
    __shared__ int sm[256];
    const int t = threadIdx.x;
    int v = (t < nb) ? bsum[t] : 0;
    int x = v;
    sm[t] = x;
    __syncthreads();
#pragma unroll
    for (int off = 1; off < 256; off <<= 1) {
        int y = (t >= off) ? sm[t - off] : 0;
        __syncthreads();
        x += y;
        sm[t] = x;
        __syncthreads();
    }
    if (t < nb) bsum[t] = x - v;  // exclusive block offsets
    if (t == 255) rowptr[N] = x;  // grand total = E
}

__global__ __launch_bounds__(256) void k_scan3(int* __restrict__ rowptr, const int* __restrict__ bsum, int N) {
    int i = blockIdx.x * 256 + threadIdx.x;
    if (i < N) rowptr[i] += bsum[blockIdx.x];
}

__global__ __launch_bounds__(256) void k_fill(const int* __restrict__ src, const int* __restrict__ dst,
                                              const int* __restrict__ rowptr, int* __restrict__ rowcnt,
                                              int* __restrict__ csr, int E) {
    int e = blockIdx.x * 256 + threadIdx.x;
    if (e < E) {
        int d = dst[e];
        int pos = rowptr[d] + atomicAdd(&rowcnt[d], 1);
        csr[pos] = src[e];
    }
}

// ---------------- weight prep: transpose + f16 convert ----------------
__global__ __launch_bounds__(256) void k_wt(const float* __restrict__ W1, const float* __restrict__ Wmu,
                                            const float* __restrict__ Wls, _Float16* __restrict__ Wt1,
                                            _Float16* __restrict__ Wct) {
    int b = blockIdx.x;
    int t = threadIdx.x;  // k index
    if (b < 256) {
        Wt1[b * 256 + t] = (_Float16)W1[t * 256 + b];
    } else {
        int j = b - 256;
        float v = (j < 128) ? Wmu[t * 128 + j] : Wls[t * 128 + (j - 128)];
        Wct[j * 256 + t] = (_Float16)v;
    }
}

// ---------------- GEMM: [M x 256] @ [256 x 256], BK=64, reg-prefetch staging ----------------
// AF32: A operand is f32 (converted during staging); else f16.
// OUTF32: write f32 to d_out split mu/ls with bias; else write f16 scaled by dinv[row].
template <int AF32, int OUTF32>
__global__ __launch_bounds__(256) void gemm_k(const void* __restrict__ Aptr, const _Float16* __restrict__ Bt,
                                              const float* __restrict__ bmu, const float* __restrict__ bls,
                                              const float* __restrict__ dinv,
                                              void* __restrict__ outp, int M, size_t split) {
    __shared__ _Float16 As[128 * LDP2];
    __shared__ _Float16 Bs[128 * LDP2];
    const int t = threadIdx.x;
    const int lane = t & 63;
    const int wid = t >> 6;
    const int bm = blockIdx.x * 128;
    const int bn = blockIdx.y * 128;
    const int wm = (wid & 1) * 64;
    const int wn = (wid >> 1) * 64;

    float4v acc[4][4];
#pragma unroll
    for (int i = 0; i < 4; i++)
#pragma unroll
        for (int j = 0; j < 4; j++) acc[i][j] = (float4v){0.f, 0.f, 0.f, 0.f};

    // prefetch registers
    float4v ar32[8];
    half8 ar16[4];
    half8 br[4];

    // A staging geometry (f32): row = t>>1, ko = (t&1)*32, 8x float4 = 32 floats
    const int a32row = t >> 1;
    const int a32ko = (t & 1) * 32;
    // A/B staging geometry (f16): unit u = m*256+t -> row=u>>3, k8=(u&7)*8

    auto load_regs = [&](int kt) {
        if (AF32) {
            const float* A = (const float*)Aptr;
            int gr = bm + a32row; if (gr >= M) gr = M - 1;
            const float4v* p = (const float4v*)(A + (size_t)gr * 256 + kt + a32ko);
#pragma unroll
            for (int q = 0; q < 8; q++) ar32[q] = p[q];
        } else {
            const _Float16* A = (const _Float16*)Aptr;
#pragma unroll
            for (int m = 0; m < 4; m++) {
                int u = m * 256 + t;
                int row = u >> 3, k8 = (u & 7) * 8;
                int gr = bm + row; if (gr >= M) gr = M - 1;
                ar16[m] = *(const half8*)(A + (size_t)gr * 256 + kt + k8);
            }
        }
#pragma unroll
        for (int m = 0; m < 4; m++) {
            int u = m * 256 + t;
            int row = u >> 3, k8 = (u & 7) * 8;
            br[m] = *(const half8*)(Bt + (size_t)(bn + row) * 256 + kt + k8);
        }
    };

    auto write_lds = [&]() {
        if (AF32) {
#pragma unroll
            for (int q = 0; q < 4; q++) {
                half8 h;
#pragma unroll
                for (int j = 0; j < 4; j++) { h[j] = (_Float16)ar32[2 * q][j]; h[4 + j] = (_Float16)ar32[2 * q + 1][j]; }
                *(half8*)&As[a32row * LDP2 + a32ko + q * 8] = h;
            }
        } else {
#pragma unroll
            for (int m = 0; m < 4; m++) {
                int u = m * 256 + t;
                int row = u >> 3, k8 = (u & 7) * 8;
                *(half8*)&As[row * LDP2 + k8] = ar16[m];
            }
        }
#pragma unroll
        for (int m = 0; m < 4; m++) {
            int u = m * 256 + t;
            int row = u >> 3, k8 = (u & 7) * 8;
            *(half8*)&Bs[row * LDP2 + k8] = br[m];
        }
    };

    load_regs(0);
#pragma unroll
    for (int it = 0; it < 4; it++) {
        if (it > 0) __syncthreads();  // all waves done reading LDS of previous tile
        write_lds();                  // vmcnt waits inserted by compiler
        __syncthreads();
        if (it < 3) load_regs((it + 1) * 64);  // issue next-tile loads; hidden under MFMA

        const int kg = (lane >> 4) * 8;
        const int fr = lane & 15;
#pragma unroll
        for (int kk = 0; kk < 64; kk += 32) {
            half8 af[4], bf[4];
#pragma unroll
            for (int f = 0; f < 4; f++) af[f] = *(const half8*)&As[(wm + f * 16 + fr) * LDP2 + kk + kg];
#pragma unroll
            for (int f = 0; f < 4; f++) bf[f] = *(const half8*)&Bs[(wn + f * 16 + fr) * LDP2 + kk + kg];
#pragma unroll
            for (int i = 0; i < 4; i++)
#pragma unroll
                for (int j = 0; j < 4; j++)
                    acc[i][j] = __builtin_amdgcn_mfma_f32_16x16x32_f16(af[i], bf[j], acc[i][j], 0, 0, 0);
        }
    }

    // ---- epilogue: D mapping col=lane&15, row=(lane>>4)*4+reg ----
    const int fc = lane & 15;
    const int rq = (lane >> 4) * 4;
    if (OUTF32) {
        float* out = (float*)outp;
#pragma unroll
        for (int i = 0; i < 4; i++) {
#pragma unroll
            for (int j = 0; j < 4; j++) {
                int col = bn + wn + j * 16 + fc;
                float bias = (col < 128) ? bmu[col] : bls[col - 128];
#pragma unroll
                for (int r = 0; r < 4; r++) {
                    int row = bm + wm + i * 16 + rq + r;
                    if (row < M) {
                        size_t o = (col < 128) ? ((size_t)row * 128 + col)
                                               : (split + (size_t)row * 128 + (col - 128));
                        out[o] = acc[i][j][r] + bias;
                    }
                }
            }
        }
    } else {
        _Float16* out = (_Float16*)outp;
#pragma unroll
        for (int i = 0; i < 4; i++) {
#pragma unroll
            for (int r = 0; r < 4; r++) {
                int row = bm + wm + i * 16 + rq + r;
                if (row < M) {
                    float sc = dinv[row];  // pre-scale rows by dinv -> agg loop needs no dinv[s]
#pragma unroll
                    for (int j = 0; j < 4; j++) {
                        int col = bn + wn + j * 16 + fc;
                        out[(size_t)row * 256 + col] = (_Float16)(acc[i][j][r] * sc);
                    }
                }
            }
        }
    }
}

// ---------------- aggregation over pre-scaled rows ----------------
// in is scaled by dinv[row]. acc = in[g] + sum_{e} in[src_e]  (pure add loop)
// MODE 1: out = relu(acc*dd + bias) * dd   (layer-1: produce scaled hb)
// MODE 0: out = acc*dd                     (layer-2: produce unscaled g)
__global__ __launch_bounds__(256) void k_agg(const _Float16* __restrict__ in, _Float16* __restrict__ out,
                                             const float* __restrict__ dinv, const int* __restrict__ rowptr,
                                             const int* __restrict__ csr, const float* __restrict__ bias,
                                             int mode, int N) {
    const int g = blockIdx.x * 4 + (threadIdx.x >> 6);
    const int lane = threadIdx.x & 63;
    if (g >= N) return;
    const float dd = dinv[g];
    const int beg = rowptr[g], end = rowptr[g + 1];
    const size_t fo = (size_t)lane * 4;

    float acc[4];
    {
        half4 hv = *(const half4*)(in + (size_t)g * 256 + fo);
#pragma unroll
        for (int j = 0; j < 4; j++) acc[j] = (float)hv[j];
    }
    int e = beg;
    for (; e + 4 <= end; e += 4) {
        int s0 = csr[e], s1 = csr[e + 1], s2 = csr[e + 2], s3 = csr[e + 3];
        half4 v0 = *(const half4*)(in + (size_t)s0 * 256 + fo);
        half4 v1 = *(const half4*)(in + (size_t)s1 * 256 + fo);
        half4 v2 = *(const half4*)(in + (size_t)s2 * 256 + fo);
        half4 v3 = *(const half4*)(in + (size_t)s3 * 256 + fo);
#pragma unroll
        for (int j = 0; j < 4; j++)
            acc[j] += (float)v0[j] + (float)v1[j] + (float)v2[j] + (float)v3[j];
    }
    for (; e < end; ++e) {
        int s = csr[e];
        half4 v = *(const half4*)(in + (size_t)s * 256 + fo);
#pragma unroll
        for (int j = 0; j < 4; j++) acc[j] += (float)v[j];
    }

    half4 o;
    if (mode) {
#pragma unroll
        for (int j = 0; j < 4; j++) {
            float r = fmaxf(acc[j] * dd + bias[lane * 4 + j], 0.f);
            o[j] = (_Float16)(r * dd);
        }
    } else {
#pragma unroll
        for (int j = 0; j < 4; j++) o[j] = (_Float16)(acc[j] * dd);
    }
    *(half4*)(out + (size_t)g * 256 + fo) = o;
}

// ---------------- launch ----------------

extern "C" void kernel_launch(void* const* d_in, const int* in_sizes, int n_in,
                              void* d_out, int out_size, void* d_ws, size_t ws_size,
                              hipStream_t stream) {
    const float* x   = (const float*)d_in[0];
    const int*   ei  = (const int*)d_in[1];
    const float* W1  = (const float*)d_in[2];
    const float* b1  = (const float*)d_in[3];
    const float* Wmu = (const float*)d_in[4];
    const float* bmu = (const float*)d_in[5];
    const float* Wls = (const float*)d_in[6];
    const float* bls = (const float*)d_in[7];
    const int N = in_sizes[0] / 256;
    const int E = in_sizes[1] / 2;
    const int* esrc = ei;
    const int* edst = ei + E;

    char* ws = (char*)d_ws;
    size_t off = 0;
    auto alloc = [&](size_t bytes) -> void* {
        void* p = ws + off;
        off += (bytes + 255) & ~(size_t)255;
        return p;
    };
    _Float16* h1  = (_Float16*)alloc((size_t)N * 256 * 2);  // h1s (scaled); reused as g (unscaled)
    _Float16* hb  = (_Float16*)alloc((size_t)N * 256 * 2);  // hbs (scaled)
    _Float16* Wt1 = (_Float16*)alloc(256 * 256 * 2);
    _Float16* Wct = (_Float16*)alloc(256 * 256 * 2);
    float* dinv   = (float*)alloc((size_t)N * 4);
    int* degcnt   = (int*)alloc((size_t)N * 2 * 4);  // [deg | rowcnt] contiguous -> one memset
    int* deg      = degcnt;
    int* rowcnt   = degcnt + N;
    int* rowptr   = (int*)alloc((size_t)(N + 1) * 4);
    int* bsum     = (int*)alloc(256 * 4);
    int* csr      = (int*)alloc((size_t)E * 4);

    const int nb = (N + 255) / 256;  // scan blocks (<=256)

    hipMemsetAsync(degcnt, 0, (size_t)N * 2 * 4, stream);

    k_deg<<<(E + 255) / 256, 256, 0, stream>>>(edst, deg, E);
    k_scan1<<<nb, 256, 0, stream>>>(deg, rowptr, bsum, dinv, N);
    k_scan2<<<1, 256, 0, stream>>>(bsum, rowptr, nb, N);
    k_scan3<<<nb, 256, 0, stream>>>(rowptr, bsum, N);
    k_fill<<<(E + 255) / 256, 256, 0, stream>>>(esrc, edst, rowptr, rowcnt, csr, E);
    k_wt<<<512, 256, 0, stream>>>(W1, Wmu, Wls, Wt1, Wct);

    dim3 gg((N + 127) / 128, 2);
    gemm_k<1, 0><<<gg, 256, 0, stream>>>(x, Wt1, nullptr, nullptr, dinv, h1, N, 0);
    k_agg<<<(N + 3) / 4, 256, 0, stream>>>(h1, hb, dinv, rowptr, csr, b1, 1, N);
    k_agg<<<(N + 3) / 4, 256, 0, stream>>>(hb, h1, dinv, rowptr, csr, nullptr, 0, N);
    gemm_k<0, 1><<<gg, 256, 0, stream>>>(h1, Wct, bmu, bls, nullptr, d_out, N, (size_t)N * 128);
}

// Round 5
// 356.993 us; speedup vs baseline: 1.3180x; 1.0104x over previous
//
#include <hip/hip_runtime.h>
#include <hip/hip_fp16.h>

typedef __attribute__((ext_vector_type(8))) _Float16 half8;
typedef __attribute__((ext_vector_type(4))) _Float16 half4;
typedef __attribute__((ext_vector_type(4))) float float4v;

#define LDP2 72  // padded LDS row stride in f16 for BK=64 (144B -> stride 36 banks -> 2-way, free)

// ---------------- degree / CSR build ----------------

__global__ __launch_bounds__(256) void k_deg(const int* __restrict__ dst, int* __restrict__ deg, int E) {
    int e = blockIdx.x * 256 + threadIdx.x;
    if (e < E) atomicAdd(&deg[dst[e]], 1);
}

// ---- parallel exclusive scan of deg -> rowptr (3 phases), dinv fused into phase 1 ----

__global__ __launch_bounds__(256) void k_scan1(const int* __restrict__ deg, int* __restrict__ rowptr,
                                               int* __restrict__ bsum, float* __restrict__ dinv, int N) {
    __shared__ int sm[256];
    const int t = threadIdx.x;
    const int i = blockIdx.x * 256 + t;
    int v = (i < N) ? deg[i] : 0;
    if (i < N) dinv[i] = rsqrtf((float)(v + 1));  // +1 = self-loop
    int x = v;
    sm[t] = x;
    __syncthreads();
#pragma unroll
    for (int off = 1; off < 256; off <<= 1) {
        int y = (t >= off) ? sm[t - off] : 0;
        __syncthreads();
        x += y;
        sm[t] = x;
        __syncthreads();
    }
    if (i < N) rowptr[i] = x - v;      // exclusive within block
    if (t == 255) bsum[blockIdx.x] = x; // block total
}

__global__ __launch_bounds__(256) void k_scan2(int* __restrict__ bsum, int* __restrict__ rowptr, int nb, int N) {
    __shared__ int sm[256];
    const int t = threadIdx.x;
    int v = (t < nb) ? bsum[t] : 0;
    int x = v;
    sm[t] = x;
    __syncthreads();
#pragma unroll
    for (int off = 1; off < 256; off <<= 1) {
        int y = (t >= off) ? sm[t - off] : 0;
        __syncthreads();
        x += y;
        sm[t] = x;
        __syncthreads();
    }
    if (t < nb) bsum[t] = x - v;  // exclusive block offsets
    if (t == 255) rowptr[N] = x;  // grand total = E
}

__global__ __launch_bounds__(256) void k_scan3(int* __restrict__ rowptr, const int* __restrict__ bsum, int N) {
    int i = blockIdx.x * 256 + threadIdx.x;
    if (i < N) rowptr[i] += bsum[blockIdx.x];
}

__global__ __launch_bounds__(256) void k_fill(const int* __restrict__ src, const int* __restrict__ dst,
                                              const int* __restrict__ rowptr, int* __restrict__ rowcnt,
                                              int* __restrict__ csr, int E) {
    int e = blockIdx.x * 256 + threadIdx.x;
    if (e < E) {
        int d = dst[e];
        int pos = rowptr[d] + atomicAdd(&rowcnt[d], 1);
        csr[pos] = src[e];
    }
}

// ---------------- weight prep: transpose + f16 convert ----------------
__global__ __launch_bounds__(256) void k_wt(const float* __restrict__ W1, const float* __restrict__ Wmu,
                                            const float* __restrict__ Wls, _Float16* __restrict__ Wt1,
                                            _Float16* __restrict__ Wct) {
    int b = blockIdx.x;
    int t = threadIdx.x;  // k index
    if (b < 256) {
        Wt1[b * 256 + t] = (_Float16)W1[t * 256 + b];
    } else {
        int j = b - 256;
        float v = (j < 128) ? Wmu[t * 128 + j] : Wls[t * 128 + (j - 128)];
        Wct[j * 256 + t] = (_Float16)v;
    }
}

// ---------------- GEMM: [M x 256] @ [256 x 256], BK=64, reg-prefetch staging ----------------
// XCD-chunked swizzle: bn is the fastest virtual axis so the 2 blocks sharing
// the same 128 A-rows run adjacently on the same XCD's L2 (halves A re-fetch).
// AF32: A operand is f32 (converted during staging); else f16.
// OUTF32: write f32 to d_out split mu/ls with bias; else write f16 scaled by dinv[row].
template <int AF32, int OUTF32>
__global__ __launch_bounds__(256) void gemm_k(const void* __restrict__ Aptr, const _Float16* __restrict__ Bt,
                                              const float* __restrict__ bmu, const float* __restrict__ bls,
                                              const float* __restrict__ dinv,
                                              void* __restrict__ outp, int M, size_t split) {
    __shared__ _Float16 As[128 * LDP2];
    __shared__ _Float16 Bs[128 * LDP2];
    const int t = threadIdx.x;
    const int lane = t & 63;
    const int wid = t >> 6;

    // bijective chunked XCD swizzle (assumes xcd = blockIdx.x % 8 round-robin)
    const int nwg = gridDim.x;
    const int wg = blockIdx.x;
    const int q8 = nwg >> 3, r8 = nwg & 7;
    const int xcd = wg & 7, pos = wg >> 3;
    const int v = (xcd < r8) ? (xcd * (q8 + 1) + pos) : (r8 * (q8 + 1) + (xcd - r8) * q8 + pos);
    const int bm = (v >> 1) * 128;
    const int bn = (v & 1) * 128;

    const int wm = (wid & 1) * 64;
    const int wn = (wid >> 1) * 64;

    float4v acc[4][4];
#pragma unroll
    for (int i = 0; i < 4; i++)
#pragma unroll
        for (int j = 0; j < 4; j++) acc[i][j] = (float4v){0.f, 0.f, 0.f, 0.f};

    // prefetch registers
    float4v ar32[8];
    half8 ar16[4];
    half8 br[4];

    const int a32row = t >> 1;
    const int a32ko = (t & 1) * 32;

    auto load_regs = [&](int kt) {
        if (AF32) {
            const float* A = (const float*)Aptr;
            int gr = bm + a32row; if (gr >= M) gr = M - 1;
            const float4v* p = (const float4v*)(A + (size_t)gr * 256 + kt + a32ko);
#pragma unroll
            for (int q = 0; q < 8; q++) ar32[q] = p[q];
        } else {
            const _Float16* A = (const _Float16*)Aptr;
#pragma unroll
            for (int m = 0; m < 4; m++) {
                int u = m * 256 + t;
                int row = u >> 3, k8 = (u & 7) * 8;
                int gr = bm + row; if (gr >= M) gr = M - 1;
                ar16[m] = *(const half8*)(A + (size_t)gr * 256 + kt + k8);
            }
        }
#pragma unroll
        for (int m = 0; m < 4; m++) {
            int u = m * 256 + t;
            int row = u >> 3, k8 = (u & 7) * 8;
            br[m] = *(const half8*)(Bt + (size_t)(bn + row) * 256 + kt + k8);
        }
    };

    auto write_lds = [&]() {
        if (AF32) {
#pragma unroll
            for (int q = 0; q < 4; q++) {
                half8 h;
#pragma unroll
                for (int j = 0; j < 4; j++) { h[j] = (_Float16)ar32[2 * q][j]; h[4 + j] = (_Float16)ar32[2 * q + 1][j]; }
                *(half8*)&As[a32row * LDP2 + a32ko + q * 8] = h;
            }
        } else {
#pragma unroll
            for (int m = 0; m < 4; m++) {
                int u = m * 256 + t;
                int row = u >> 3, k8 = (u & 7) * 8;
                *(half8*)&As[row * LDP2 + k8] = ar16[m];
            }
        }
#pragma unroll
        for (int m = 0; m < 4; m++) {
            int u = m * 256 + t;
            int row = u >> 3, k8 = (u & 7) * 8;
            *(half8*)&Bs[row * LDP2 + k8] = br[m];
        }
    };

    load_regs(0);
#pragma unroll
    for (int it = 0; it < 4; it++) {
        if (it > 0) __syncthreads();
        write_lds();
        __syncthreads();
        if (it < 3) load_regs((it + 1) * 64);  // next-tile loads hidden under MFMA

        const int kg = (lane >> 4) * 8;
        const int fr = lane & 15;
#pragma unroll
        for (int kk = 0; kk < 64; kk += 32) {
            half8 af[4], bf[4];
#pragma unroll
            for (int f = 0; f < 4; f++) af[f] = *(const half8*)&As[(wm + f * 16 + fr) * LDP2 + kk + kg];
#pragma unroll
            for (int f = 0; f < 4; f++) bf[f] = *(const half8*)&Bs[(wn + f * 16 + fr) * LDP2 + kk + kg];
#pragma unroll
            for (int i = 0; i < 4; i++)
#pragma unroll
                for (int j = 0; j < 4; j++)
                    acc[i][j] = __builtin_amdgcn_mfma_f32_16x16x32_f16(af[i], bf[j], acc[i][j], 0, 0, 0);
        }
    }

    // ---- epilogue: D mapping col=lane&15, row=(lane>>4)*4+reg ----
    const int fc = lane & 15;
    const int rq = (lane >> 4) * 4;
    if (OUTF32) {
        float* out = (float*)outp;
#pragma unroll
        for (int i = 0; i < 4; i++) {
#pragma unroll
            for (int j = 0; j < 4; j++) {
                int col = bn + wn + j * 16 + fc;
                float bias = (col < 128) ? bmu[col] : bls[col - 128];
#pragma unroll
                for (int r = 0; r < 4; r++) {
                    int row = bm + wm + i * 16 + rq + r;
                    if (row < M) {
                        size_t o = (col < 128) ? ((size_t)row * 128 + col)
                                               : (split + (size_t)row * 128 + (col - 128));
                        out[o] = acc[i][j][r] + bias;
                    }
                }
            }
        }
    } else {
        _Float16* out = (_Float16*)outp;
#pragma unroll
        for (int i = 0; i < 4; i++) {
#pragma unroll
            for (int r = 0; r < 4; r++) {
                int row = bm + wm + i * 16 + rq + r;
                if (row < M) {
                    float sc = dinv[row];  // pre-scale rows by dinv -> agg loop needs no dinv[s]
#pragma unroll
                    for (int j = 0; j < 4; j++) {
                        int col = bn + wn + j * 16 + fc;
                        out[(size_t)row * 256 + col] = (_Float16)(acc[i][j][r] * sc);
                    }
                }
            }
        }
    }
}

// ---------------- aggregation over pre-scaled rows ----------------
// One 64-lane wave per node. 16B/lane: lanes 0-31 cover the row for even edges,
// lanes 32-63 for odd edges (zero divergence); merged via shfl_xor(32) at end.
// 1-deep software pipeline: rows for quad q+1 in flight while accumulating quad q.
// MODE 1: out = relu(acc*dd + bias) * dd   MODE 0: out = acc*dd
__global__ __launch_bounds__(128) void k_agg(const _Float16* __restrict__ in, _Float16* __restrict__ out,
                                             const float* __restrict__ dinv, const int* __restrict__ rowptr,
                                             const int* __restrict__ csr, const float* __restrict__ bias,
                                             int mode, int N) {
    const int g = blockIdx.x * 2 + (threadIdx.x >> 6);
    if (g >= N) return;
    const int lane = threadIdx.x & 63;
    const int half = lane >> 5;
    const int fl = lane & 31;
    const size_t fo = (size_t)fl * 8;
    const _Float16* __restrict__ base = in + fo;

    const int beg = rowptr[g], end = rowptr[g + 1];
    const int nq = (end - beg) >> 2;

    float acc[8];
    if (half == 0) {
        half8 sv = *(const half8*)(base + (size_t)g * 256);
#pragma unroll
        for (int j = 0; j < 8; j++) acc[j] = (float)sv[j];
    } else {
#pragma unroll
        for (int j = 0; j < 8; j++) acc[j] = 0.f;
    }

    int p = beg + half;  // this lane handles edges p, p+2 within each quad
    half8 va, vb;
    if (nq > 0) {
        int ia = csr[p], ib = csr[p + 2];
        va = *(const half8*)(base + (size_t)ia * 256);
        vb = *(const half8*)(base + (size_t)ib * 256);
    }
    for (int q = 0; q + 1 < nq; q++) {
        int na = csr[p + 4], nb = csr[p + 6];
        half8 wa = *(const half8*)(base + (size_t)na * 256);
        half8 wb = *(const half8*)(base + (size_t)nb * 256);
#pragma unroll
        for (int j = 0; j < 8; j++) acc[j] += (float)va[j];
#pragma unroll
        for (int j = 0; j < 8; j++) acc[j] += (float)vb[j];
        va = wa; vb = wb;
        p += 4;
    }
    if (nq > 0) {
#pragma unroll
        for (int j = 0; j < 8; j++) acc[j] += (float)va[j];
#pragma unroll
        for (int j = 0; j < 8; j++) acc[j] += (float)vb[j];
    }
    for (int e = beg + 4 * nq + half; e < end; e += 2) {
        int s = csr[e];
        half8 v = *(const half8*)(base + (size_t)s * 256);
#pragma unroll
        for (int j = 0; j < 8; j++) acc[j] += (float)v[j];
    }

#pragma unroll
    for (int j = 0; j < 8; j++) acc[j] += __shfl_xor(acc[j], 32);

    if (half == 0) {
        const float dd = dinv[g];
        half8 o;
        if (mode) {
            const float4v* bp = (const float4v*)(bias + fl * 8);
            float4v b0 = bp[0], b1 = bp[1];
#pragma unroll
            for (int j = 0; j < 4; j++) {
                float r0 = fmaxf(acc[j] * dd + b0[j], 0.f);
                o[j] = (_Float16)(r0 * dd);
                float r1 = fmaxf(acc[4 + j] * dd + b1[j], 0.f);
                o[4 + j] = (_Float16)(r1 * dd);
            }
        } else {
#pragma unroll
            for (int j = 0; j < 8; j++) o[j] = (_Float16)(acc[j] * dd);
        }
        *(half8*)(out + (size_t)g * 256 + fo) = o;
    }
}

// ---------------- launch ----------------

extern "C" void kernel_launch(void* const* d_in, const int* in_sizes, int n_in,
                              void* d_out, int out_size, void* d_ws, size_t ws_size,
                              hipStream_t stream) {
    const float* x   = (const float*)d_in[0];
    const int*   ei  = (const int*)d_in[1];
    const float* W1  = (const float*)d_in[2];
    const float* b1  = (const float*)d_in[3];
    const float* Wmu = (const float*)d_in[4];
    const float* bmu = (const float*)d_in[5];
    const float* Wls = (const float*)d_in[6];
    const float* bls = (const float*)d_in[7];
    const int N = in_sizes[0] / 256;
    const int E = in_sizes[1] / 2;
    const int* esrc = ei;
    const int* edst = ei + E;

    char* ws = (char*)d_ws;
    size_t off = 0;
    auto alloc = [&](size_t bytes) -> void* {
        void* p = ws + off;
        off += (bytes + 255) & ~(size_t)255;
        return p;
    };
    _Float16* h1  = (_Float16*)alloc((size_t)N * 256 * 2);  // h1s (scaled); reused as g (unscaled)
    _Float16* hb  = (_Float16*)alloc((size_t)N * 256 * 2);  // hbs (scaled)
    _Float16* Wt1 = (_Float16*)alloc(256 * 256 * 2);
    _Float16* Wct = (_Float16*)alloc(256 * 256 * 2);
    float* dinv   = (float*)alloc((size_t)N * 4);
    int* degcnt   = (int*)alloc((size_t)N * 2 * 4);  // [deg | rowcnt] contiguous -> one memset
    int* deg      = degcnt;
    int* rowcnt   = degcnt + N;
    int* rowptr   = (int*)alloc((size_t)(N + 1) * 4);
    int* bsum     = (int*)alloc(256 * 4);
    int* csr      = (int*)alloc((size_t)E * 4);

    const int nb = (N + 255) / 256;  // scan blocks (<=256)

    hipMemsetAsync(degcnt, 0, (size_t)N * 2 * 4, stream);

    k_deg<<<(E + 255) / 256, 256, 0, stream>>>(edst, deg, E);
    k_scan1<<<nb, 256, 0, stream>>>(deg, rowptr, bsum, dinv, N);
    k_scan2<<<1, 256, 0, stream>>>(bsum, rowptr, nb, N);
    k_scan3<<<nb, 256, 0, stream>>>(rowptr, bsum, N);
    k_fill<<<(E + 255) / 256, 256, 0, stream>>>(esrc, edst, rowptr, rowcnt, csr, E);
    k_wt<<<512, 256, 0, stream>>>(W1, Wmu, Wls, Wt1, Wct);

    const int nbm = (N + 127) / 128;
    gemm_k<1, 0><<<nbm * 2, 256, 0, stream>>>(x, Wt1, nullptr, nullptr, dinv, h1, N, 0);
    k_agg<<<(N + 1) / 2, 128, 0, stream>>>(h1, hb, dinv, rowptr, csr, b1, 1, N);
    k_agg<<<(N + 1) / 2, 128, 0, stream>>>(hb, h1, dinv, rowptr, csr, nullptr, 0, N);
    gemm_k<0, 1><<<nbm * 2, 256, 0, stream>>>(h1, Wct, bmu, bls, nullptr, d_out, N, (size_t)N * 128);
}